// Round 4
// baseline (381.586 us; speedup 1.0000x reference)
//
#include <hip/hip_runtime.h>

#define NUM_NET 2
#define V 100000
#define D 128
#define B 4096
#define K 5
#define NS 10

#define NROWS  400000          // 4 sub-tables x V rows; g = tab*V + idx
#define NUNITS 8192
#define NENT   144             // 143 real entries + 1 pad
#define SLOTS  12
#define OVF_CAP 16384

// weight magnitudes (sign encoded in bit0 of the 3-bit code)
#define W_MAIN_POS (1.0f/20480.0f)   // 1/(B*K)
#define W_INV_B    (1.0f/4096.0f)    // 1/B
#define HYP_B      (0.1f/4096.0f)    // HYP{1,2,3}/B
#define HYP2_BK    (0.1f/20480.0f)   // HYP2/(B*K)
// code: 0=+W_MAIN_POS  3=-W_INV_B  4=+HYP_B  5=-HYP_B  6=+HYP2_BK  7=pad(0)

// ---- ws layout (ints) ----
#define WS_COUNTS 0                        // NROWS ints
#define WS_CURSOR 400000                   // 1 int
#define WS_U      400064                   // 8192*128 floats = 1048576
#define WS_SLOTS  1448640                  // NROWS*SLOTS ints = 4800000
#define WS_OVF    6248640                  // OVF_CAP*2 ints = 32768
#define WS_NEEDED ((size_t)(6281408) * 4)  // ~25.1 MB

__device__ __forceinline__ float dot8(float4 a0, float4 a1, float4 b0, float4 b1) {
    return a0.x*b0.x + a0.y*b0.y + a0.z*b0.z + a0.w*b0.w
         + a1.x*b1.x + a1.y*b1.y + a1.z*b1.z + a1.w*b1.w;
}

__device__ __forceinline__ float wlogsig(float pp, int code) {
    float mag = (code == 0) ? W_MAIN_POS
              : (code == 3) ? W_INV_B
              : (code == 6) ? HYP2_BK
              : (code == 7) ? 0.0f
              : HYP_B;
    float x  = (code & 1) ? -pp : pp;
    float ls = fminf(x, 0.0f) - __logf(1.0f + __expf(-fabsf(x)));
    return mag * ls;
}

// ---------------- phase 1: gather node embeddings into U (4 MB) ----------------
__global__ __launch_bounds__(256) void rmne_build_u(
    const float* __restrict__ node_tables,
    const int*   __restrict__ nodes_idx,
    float*       __restrict__ ws)
{
    float4* U4 = (float4*)(ws + WS_U);
    int t = blockIdx.x * 256 + threadIdx.x;      // 262144 threads = 8192 units * 32 float4
    int u = t >> 5;
    int k = t & 31;
    int i = u >> 12;
    int nrow = nodes_idx[u];                     // nodes_idx is (2,4096) flat = unit order
    const float4* src = (const float4*)(node_tables + ((size_t)i*V + (size_t)nrow)*D);
    U4[(size_t)u*32 + k] = src[k];
}

// ---------------- phase 2: invert reference lists into per-row buckets ----------------
__global__ __launch_bounds__(256) void rmne_scatter(
    const int* __restrict__ nodes_idx,
    const int* __restrict__ neigh_idx,
    const int* __restrict__ role_idx,
    const int* __restrict__ neg_main,
    const int* __restrict__ neg_node,
    const int* __restrict__ neg_cross,
    const int* __restrict__ neg_role,
    int*       __restrict__ ws_i)
{
    int* counts = ws_i + WS_COUNTS;
    int* cursor = ws_i + WS_CURSOR;
    int* slots  = ws_i + WS_SLOTS;
    int* ovf    = ws_i + WS_OVF;

    int gid = blockIdx.x * 256 + threadIdx.x;    // 8192*144 = 1179648 threads
    int u = gid / NENT;
    int e = gid - u * NENT;
    int i = u >> 12;
    int b = u & (B - 1);
    int j = 1 - i;

    int idx, tab, code;
    if      (e <   5) { idx = neigh_idx[(i*B + b)*K + e];              tab = 2 + i; code = 0; }
    else if (e <  55) { idx = neg_main[(i*B + b)*50 + (e-5)];          tab = 2 + i; code = 3; }
    else if (e <  56) { idx = nodes_idx[i*B + b];                      tab = j;     code = 4; }
    else if (e <  66) { idx = neg_node[((i*2+j)*B + b)*NS + (e-56)];   tab = j;     code = 5; }
    else if (e <  71) { idx = neigh_idx[(i*B + b)*K + (e-66)];         tab = 2 + j; code = 6; }
    else if (e < 121) { idx = neg_cross[((i*2+j)*B + b)*50 + (e-71)];  tab = 2 + j; code = 5; }
    else if (e < 122) { idx = role_idx[(i*2+0)*B + b];                 tab = 0;     code = 4; }
    else if (e < 132) { idx = neg_role[((i*2+0)*B + b)*NS + (e-122)];  tab = 0;     code = 5; }
    else if (e < 133) { idx = role_idx[(i*2+1)*B + b];                 tab = 1;     code = 4; }
    else if (e < 143) { idx = neg_role[((i*2+1)*B + b)*NS + (e-133)];  tab = 1;     code = 5; }
    else return;                                 // e == 143 pad

    int g = tab * V + idx;
    int pack = u | (code << 13);
    int s = atomicAdd(&counts[g], 1);
    if (s < SLOTS) {
        slots[(size_t)g * SLOTS + s] = pack;
    } else {
        int o = atomicAdd(cursor, 1);
        if (o < OVF_CAP) { ovf[2*o] = g; ovf[2*o + 1] = pack; }
    }
}

// ---------------- phase 3: sequential stream over table rows ----------------
__global__ __launch_bounds__(256) void rmne_stream(
    const float* __restrict__ node_tables,
    const float* __restrict__ neigh_tables,
    const float* __restrict__ ws,
    float*       __restrict__ out)
{
    const int* ws_i   = (const int*)ws;
    const int* counts = ws_i + WS_COUNTS;
    const int* slots  = ws_i + WS_SLOTS;
    const int* ovf    = ws_i + WS_OVF;
    const float* U    = ws + WS_U;

    const int tid     = threadIdx.x;
    const int lane    = tid & 63;
    const int wave    = tid >> 6;
    const int l16     = lane & 15;
    const int quarter = lane >> 4;
    const int qid     = (blockIdx.x * 4 + wave) * 4 + quarter;   // 32768 quarter-tasks
    const int QTOT    = 2048 * 16;

    float acc = 0.0f;

    for (int g = qid; g < NROWS; g += QTOT) {
        int c = counts[g];
        if (c == 0) continue;
        const float* rowb = (g < 2*V) ? node_tables + (size_t)g * D
                                      : neigh_tables + (size_t)(g - 2*V) * D;
        const float4* row = (const float4*)rowb + l16*2;
        float4 r0 = row[0];
        float4 r1 = row[1];
        int cc = (c < SLOTS) ? c : SLOTS;
        for (int s = 0; s < cc; ++s) {
            int p = slots[(size_t)g * SLOTS + s];
            int u = p & (NUNITS - 1);
            int code = p >> 13;
            const float4* up = (const float4*)(U + (size_t)u * D) + l16*2;
            float pp = dot8(r0, r1, up[0], up[1]);
            pp += __shfl_xor(pp, 1, 64);
            pp += __shfl_xor(pp, 2, 64);
            pp += __shfl_xor(pp, 4, 64);
            pp += __shfl_xor(pp, 8, 64);
            acc += wlogsig(pp, code);
        }
    }

    // overflow entries (statistically ~0, but must be correct)
    int n_ovf = ws_i[WS_CURSOR];
    if (n_ovf > OVF_CAP) n_ovf = OVF_CAP;
    for (int o = qid; o < n_ovf; o += QTOT) {
        int g = ovf[2*o];
        int p = ovf[2*o + 1];
        int u = p & (NUNITS - 1);
        int code = p >> 13;
        const float* rowb = (g < 2*V) ? node_tables + (size_t)g * D
                                      : neigh_tables + (size_t)(g - 2*V) * D;
        const float4* row = (const float4*)rowb + l16*2;
        const float4* up  = (const float4*)(U + (size_t)u * D) + l16*2;
        float pp = dot8(row[0], row[1], up[0], up[1]);
        pp += __shfl_xor(pp, 1, 64);
        pp += __shfl_xor(pp, 2, 64);
        pp += __shfl_xor(pp, 4, 64);
        pp += __shfl_xor(pp, 8, 64);
        acc += wlogsig(pp, code);
    }

    // acc replicated within each quarter; xor16+xor32 adds one rep per quarter
    acc += __shfl_xor(acc, 16, 64);
    acc += __shfl_xor(acc, 32, 64);

    __shared__ float wsum[4];
    if (lane == 0) wsum[wave] = acc;
    __syncthreads();
    if (tid == 0) {
        float s = wsum[0] + wsum[1] + wsum[2] + wsum[3];
        atomicAdd(out, s * (-1.0f / 10.0f));
    }
}

// ---------------- fallback: proven R1 direct-gather kernel ----------------
__global__ __launch_bounds__(256) void rmne_gather(
    const float* __restrict__ node_tables,
    const float* __restrict__ neigh_tables,
    const int*   __restrict__ nodes_idx,
    const int*   __restrict__ neigh_idx,
    const int*   __restrict__ role_idx,
    const int*   __restrict__ neg_main,
    const int*   __restrict__ neg_node,
    const int*   __restrict__ neg_cross,
    const int*   __restrict__ neg_role,
    float*       __restrict__ out)
{
    const int tid  = threadIdx.x;
    const int lane = tid & 63;
    const int wave = tid >> 6;
    const int unit = blockIdx.x * 4 + wave;
    const int i = unit >> 12;
    const int b = unit & (B - 1);
    const int j = 1 - i;

    int   pk[3];
    float wv[3];
    #pragma unroll
    for (int s = 0; s < 3; ++s) {
        int d = lane + 64 * s;
        int idx = 0; float w = 0.0f; int tab = 0;
        if      (d <   5) { idx = neigh_idx[(i*B + b)*K + d];              w =  W_MAIN_POS; tab = 2 + i; }
        else if (d <  55) { idx = neg_main[(i*B + b)*50 + (d-5)];          w = -W_INV_B;    tab = 2 + i; }
        else if (d <  56) { idx = nodes_idx[i*B + b];                      w =  HYP_B;      tab = j;     }
        else if (d <  66) { idx = neg_node[((i*2+j)*B + b)*NS + (d-56)];   w = -HYP_B;      tab = j;     }
        else if (d <  71) { idx = neigh_idx[(i*B + b)*K + (d-66)];         w =  HYP2_BK;    tab = 2 + j; }
        else if (d < 121) { idx = neg_cross[((i*2+j)*B + b)*50 + (d-71)];  w = -HYP_B;      tab = 2 + j; }
        else if (d < 122) { idx = role_idx[(i*2+0)*B + b];                 w =  HYP_B;      tab = 0;     }
        else if (d < 132) { idx = neg_role[((i*2+0)*B + b)*NS + (d-122)];  w = -HYP_B;      tab = 0;     }
        else if (d < 133) { idx = role_idx[(i*2+1)*B + b];                 w =  HYP_B;      tab = 1;     }
        else if (d < 143) { idx = neg_role[((i*2+1)*B + b)*NS + (d-133)];  w = -HYP_B;      tab = 1;     }
        pk[s] = idx | (tab << 20);
        wv[s] = w;
    }

    const int l16     = lane & 15;
    const int quarter = lane >> 4;
    const int nrow    = nodes_idx[i*B + b];
    const float4* nep = (const float4*)(node_tables + ((size_t)i*V + (size_t)nrow)*D) + l16*2;
    const float4 ne0 = nep[0];
    const float4 ne1 = nep[1];

    float acc = 0.0f;

    auto do_iter = [&](int t, int pks, float wvs) {
        int   src = (4*t + quarter) & 63;
        int   p   = __shfl(pks, src, 64);
        float w   = __shfl(wvs, src, 64);
        int idx = p & 0xFFFFF;
        int tab = p >> 20;
        const float* base = (tab & 2) ? neigh_tables : node_tables;
        const float4* row = (const float4*)(base + ((size_t)(tab & 1)*V + (size_t)idx)*D) + l16*2;
        float4 c0 = row[0];
        float4 c1 = row[1];
        float pp = dot8(ne0, ne1, c0, c1);
        pp += __shfl_xor(pp, 1, 64);
        pp += __shfl_xor(pp, 2, 64);
        pp += __shfl_xor(pp, 4, 64);
        pp += __shfl_xor(pp, 8, 64);
        float x  = (w < 0.0f) ? -pp : pp;
        float ls = fminf(x, 0.0f) - __logf(1.0f + __expf(-fabsf(x)));
        acc += fabsf(w) * ls;
    };

    #pragma unroll 4
    for (int t = 0;  t < 16; ++t) do_iter(t, pk[0], wv[0]);
    #pragma unroll 4
    for (int t = 16; t < 32; ++t) do_iter(t, pk[1], wv[1]);
    #pragma unroll
    for (int t = 32; t < 36; ++t) do_iter(t, pk[2], wv[2]);

    acc += __shfl_xor(acc, 16, 64);
    acc += __shfl_xor(acc, 32, 64);

    __shared__ float wsum[4];
    if (lane == 0) wsum[wave] = acc;
    __syncthreads();
    if (tid == 0) {
        float s = wsum[0] + wsum[1] + wsum[2] + wsum[3];
        atomicAdd(out, s * (-1.0f / 10.0f));
    }
}

extern "C" void kernel_launch(void* const* d_in, const int* in_sizes, int n_in,
                              void* d_out, int out_size, void* d_ws, size_t ws_size,
                              hipStream_t stream) {
    const float* node_tables  = (const float*)d_in[0];
    const float* neigh_tables = (const float*)d_in[1];
    const int*   nodes_idx    = (const int*)d_in[2];
    const int*   neigh_idx    = (const int*)d_in[3];
    const int*   role_idx     = (const int*)d_in[4];
    const int*   neg_main     = (const int*)d_in[5];
    const int*   neg_node     = (const int*)d_in[6];
    const int*   neg_cross    = (const int*)d_in[7];
    const int*   neg_role     = (const int*)d_in[8];
    float* out = (float*)d_out;

    hipMemsetAsync(out, 0, sizeof(float), stream);

    if (ws_size >= WS_NEEDED) {
        float* ws = (float*)d_ws;
        // zero counts + cursor (first 400064 ints)
        hipMemsetAsync(d_ws, 0, (size_t)(WS_U) * 4, stream);
        rmne_build_u<<<1024, 256, 0, stream>>>(node_tables, nodes_idx, ws);
        rmne_scatter<<<4608, 256, 0, stream>>>(nodes_idx, neigh_idx, role_idx,
                                               neg_main, neg_node, neg_cross, neg_role,
                                               (int*)d_ws);
        rmne_stream<<<2048, 256, 0, stream>>>(node_tables, neigh_tables, ws, out);
    } else {
        rmne_gather<<<2048, 256, 0, stream>>>(node_tables, neigh_tables, nodes_idx, neigh_idx,
                                              role_idx, neg_main, neg_node, neg_cross, neg_role, out);
    }
}

// Round 5
// 295.287 us; speedup vs baseline: 1.2923x; 1.2923x over previous
//
#include <hip/hip_runtime.h>

#define NUM_NET 2
#define V 100000
#define D 128
#define B 4096
#define K 5
#define NS 10

// weight magnitudes (sign encoded in bit0 of the 3-bit code)
#define W_MAIN_POS (1.0f/20480.0f)   // 1/(B*K)
#define W_INV_B    (1.0f/4096.0f)    // 1/B
#define HYP_B      (0.1f/4096.0f)    // HYP{1,2,3}/B
#define HYP2_BK    (0.1f/20480.0f)   // HYP2/(B*K)
// code: 0=+W_MAIN_POS  3=-W_INV_B  4=+HYP_B  5=-HYP_B  6=+HYP2_BK  7=pad(0)

#define GLOBAL_AS __attribute__((address_space(1)))
#define LDS_AS    __attribute__((address_space(3)))

__device__ __forceinline__ void gl_lds16(const float* g, float* l) {
    __builtin_amdgcn_global_load_lds((const GLOBAL_AS unsigned int*)g,
                                     (LDS_AS unsigned int*)l, 16, 0, 0);
}

__device__ __forceinline__ float dot8(float4 a0, float4 a1, float4 b0, float4 b1) {
    return a0.x*b0.x + a0.y*b0.y + a0.z*b0.z + a0.w*b0.w
         + a1.x*b1.x + a1.y*b1.y + a1.z*b1.z + a1.w*b1.w;
}

__device__ __forceinline__ float wlogsig(float pp, int code) {
    float mag = (code == 0) ? W_MAIN_POS
              : (code == 3) ? W_INV_B
              : (code == 6) ? HYP2_BK
              : (code == 7) ? 0.0f
              : HYP_B;
    float x  = (code & 1) ? -pp : pp;
    float ls = fminf(x, 0.0f) - __logf(1.0f + __expf(-fabsf(x)));
    return mag * ls;
}

__global__ __launch_bounds__(256) void rmne_main(
    const float* __restrict__ node_tables,
    const float* __restrict__ neigh_tables,
    const int*   __restrict__ nodes_idx,
    const int*   __restrict__ neigh_idx,
    const int*   __restrict__ role_idx,
    const int*   __restrict__ neg_main,
    const int*   __restrict__ neg_node,
    const int*   __restrict__ neg_cross,
    const int*   __restrict__ neg_role,
    float*       __restrict__ out)
{
    // per-wave double buffer: 8 entries x 512 B = 4 KB per buffer
    __shared__ float lbuf[4][2][1024];

    const int tid  = threadIdx.x;
    const int lane = tid & 63;
    const int wave = tid >> 6;
    const int unit = blockIdx.x * 4 + wave;   // 8192 units
    const int i = unit >> 12;                 // net index (0/1)
    const int b = unit & (B - 1);
    const int j = 1 - i;

    // ---- build the 144-entry dot list; entry d at lane d&63, slot d>>6 ----
    int pk[3];
    #pragma unroll
    for (int s = 0; s < 3; ++s) {
        int d = lane + 64 * s;
        int idx = 0, tab = 0, code = 7;
        if      (d <   5) { idx = neigh_idx[(i*B + b)*K + d];              tab = 2 + i; code = 0; }
        else if (d <  55) { idx = neg_main[(i*B + b)*50 + (d-5)];          tab = 2 + i; code = 3; }
        else if (d <  56) { idx = nodes_idx[i*B + b];                      tab = j;     code = 4; }
        else if (d <  66) { idx = neg_node[((i*2+j)*B + b)*NS + (d-56)];   tab = j;     code = 5; }
        else if (d <  71) { idx = neigh_idx[(i*B + b)*K + (d-66)];         tab = 2 + j; code = 6; }
        else if (d < 121) { idx = neg_cross[((i*2+j)*B + b)*50 + (d-71)];  tab = 2 + j; code = 5; }
        else if (d < 122) { idx = role_idx[(i*2+0)*B + b];                 tab = 0;     code = 4; }
        else if (d < 132) { idx = neg_role[((i*2+0)*B + b)*NS + (d-122)];  tab = 0;     code = 5; }
        else if (d < 133) { idx = role_idx[(i*2+1)*B + b];                 tab = 1;     code = 4; }
        else if (d < 143) { idx = neg_role[((i*2+1)*B + b)*NS + (d-133)];  tab = 1;     code = 5; }
        pk[s] = idx | (tab << 20) | (code << 22);
    }

    // ---- node embedding fragment: quarter-wave layout, 8 dims/lane ----
    const int l16     = lane & 15;
    const int quarter = lane >> 4;
    const int nrow    = nodes_idx[i*B + b];
    const float4* nep = (const float4*)(node_tables + ((size_t)i*V + (size_t)nrow)*D) + l16*2;
    const float4 ne0 = nep[0];
    const float4 ne1 = nep[1];

    float acc = 0.0f;

    // issue batch bb (entries 8bb..8bb+7) as 4 async 1KB gathers (2 rows each)
    auto issue = [&](int bb, int parity) {
        float* Lb = &lbuf[wave][parity][0];
        #pragma unroll
        for (int t = 0; t < 4; ++t) {
            int e = 8*bb + 2*t + (lane >> 5);            // per-lane entry (halves differ)
            int p = __shfl(pk[bb >> 3], e & 63, 64);
            int idx = p & 0xFFFFF;
            int tab = (p >> 20) & 3;
            const float* base = (tab & 2) ? neigh_tables : node_tables;
            const float* g = base + ((size_t)(tab & 1)*V + (size_t)idx)*D + (lane & 31)*4;
            gl_lds16(g, Lb + t*256);                     // LDS dest wave-uniform
        }
    };

    // compute batch bb from its LDS buffer (2 iterations x 4 quarters)
    auto compute = [&](int bb, int parity) {
        const float* Lb = &lbuf[wave][parity][0];
        #pragma unroll
        for (int it = 0; it < 2; ++it) {
            int ein = 4*it + quarter;                    // entry within batch
            int p = __shfl(pk[bb >> 3], (8*bb + ein) & 63, 64);
            const float4* r = (const float4*)(Lb + ein*128 + l16*8);
            float4 c0 = r[0];
            float4 c1 = r[1];
            float pp = dot8(ne0, ne1, c0, c1);
            pp += __shfl_xor(pp, 1, 64);
            pp += __shfl_xor(pp, 2, 64);
            pp += __shfl_xor(pp, 4, 64);
            pp += __shfl_xor(pp, 8, 64);
            acc += wlogsig(pp, (p >> 22) & 7);
        }
    };

    issue(0, 0);
    #pragma unroll
    for (int bb = 0; bb < 17; ++bb) {
        issue(bb + 1, (bb + 1) & 1);
        asm volatile("s_waitcnt vmcnt(4)" ::: "memory");  // batch bb's 4 loads done
        compute(bb, bb & 1);
    }
    asm volatile("s_waitcnt vmcnt(0)" ::: "memory");
    compute(17, 1);

    // acc replicated within each quarter; xor16+xor32 adds one rep per quarter
    acc += __shfl_xor(acc, 16, 64);
    acc += __shfl_xor(acc, 32, 64);

    __shared__ float wsum[4];
    if (lane == 0) wsum[wave] = acc;
    __syncthreads();
    if (tid == 0) {
        float s = wsum[0] + wsum[1] + wsum[2] + wsum[3];
        atomicAdd(out, s * (-1.0f / 10.0f));
    }
}

extern "C" void kernel_launch(void* const* d_in, const int* in_sizes, int n_in,
                              void* d_out, int out_size, void* d_ws, size_t ws_size,
                              hipStream_t stream) {
    const float* node_tables  = (const float*)d_in[0];
    const float* neigh_tables = (const float*)d_in[1];
    const int*   nodes_idx    = (const int*)d_in[2];
    const int*   neigh_idx    = (const int*)d_in[3];
    const int*   role_idx     = (const int*)d_in[4];
    const int*   neg_main     = (const int*)d_in[5];
    const int*   neg_node     = (const int*)d_in[6];
    const int*   neg_cross    = (const int*)d_in[7];
    const int*   neg_role     = (const int*)d_in[8];
    float* out = (float*)d_out;

    hipMemsetAsync(out, 0, sizeof(float), stream);
    rmne_main<<<2048, 256, 0, stream>>>(node_tables, neigh_tables, nodes_idx, neigh_idx,
                                        role_idx, neg_main, neg_node, neg_cross, neg_role, out);
}

// Round 6
// 276.680 us; speedup vs baseline: 1.3792x; 1.0673x over previous
//
#include <hip/hip_runtime.h>

#define NUM_NET 2
#define V 100000
#define D 128
#define B 4096
#define K 5
#define NS 10

// weight magnitudes (sign encoded in bit0 of the 3-bit code)
#define W_MAIN_POS (1.0f/20480.0f)   // 1/(B*K)
#define W_INV_B    (1.0f/4096.0f)    // 1/B
#define HYP_B      (0.1f/4096.0f)    // HYP{1,2,3}/B
#define HYP2_BK    (0.1f/20480.0f)   // HYP2/(B*K)
// code: 0=+W_MAIN_POS  3=-W_INV_B  4=+HYP_B  5=-HYP_B  6=+HYP2_BK  7=pad(0)

__device__ __forceinline__ float dot8(float4 a0, float4 a1, float4 b0, float4 b1) {
    return a0.x*b0.x + a0.y*b0.y + a0.z*b0.z + a0.w*b0.w
         + a1.x*b1.x + a1.y*b1.y + a1.z*b1.z + a1.w*b1.w;
}

__device__ __forceinline__ float wlogsig(float pp, int code) {
    float mag = (code == 0) ? W_MAIN_POS
              : (code == 3) ? W_INV_B
              : (code == 6) ? HYP2_BK
              : (code == 7) ? 0.0f
              : HYP_B;
    float x  = (code & 1) ? -pp : pp;
    float ls = fminf(x, 0.0f) - __logf(1.0f + __expf(-fabsf(x)));
    return mag * ls;
}

__global__ __launch_bounds__(256) void rmne_main(
    const float* __restrict__ node_tables,
    const float* __restrict__ neigh_tables,
    const int*   __restrict__ nodes_idx,
    const int*   __restrict__ neigh_idx,
    const int*   __restrict__ role_idx,
    const int*   __restrict__ neg_main,
    const int*   __restrict__ neg_node,
    const int*   __restrict__ neg_cross,
    const int*   __restrict__ neg_role,
    float*       __restrict__ out)
{
    const int tid  = threadIdx.x;
    const int lane = tid & 63;
    const int wave = tid >> 6;
    const int unit = blockIdx.x * 4 + wave;   // 8192 units
    const int i = unit >> 12;                 // net index (0/1)
    const int b = unit & (B - 1);
    const int j = 1 - i;

    // ---- build the 144-entry dot list; entry d at lane d&63, slot d>>6 ----
    // d >= 143 (incl. the wrap region used by the pipeline tail) -> code 7, idx 0 (zero weight)
    int pk[3];
    #pragma unroll
    for (int s = 0; s < 3; ++s) {
        int d = lane + 64 * s;
        int idx = 0, tab = 0, code = 7;
        if      (d <   5) { idx = neigh_idx[(i*B + b)*K + d];              tab = 2 + i; code = 0; }
        else if (d <  55) { idx = neg_main[(i*B + b)*50 + (d-5)];          tab = 2 + i; code = 3; }
        else if (d <  56) { idx = nodes_idx[i*B + b];                      tab = j;     code = 4; }
        else if (d <  66) { idx = neg_node[((i*2+j)*B + b)*NS + (d-56)];   tab = j;     code = 5; }
        else if (d <  71) { idx = neigh_idx[(i*B + b)*K + (d-66)];         tab = 2 + j; code = 6; }
        else if (d < 121) { idx = neg_cross[((i*2+j)*B + b)*50 + (d-71)];  tab = 2 + j; code = 5; }
        else if (d < 122) { idx = role_idx[(i*2+0)*B + b];                 tab = 0;     code = 4; }
        else if (d < 132) { idx = neg_role[((i*2+0)*B + b)*NS + (d-122)];  tab = 0;     code = 5; }
        else if (d < 133) { idx = role_idx[(i*2+1)*B + b];                 tab = 1;     code = 4; }
        else if (d < 143) { idx = neg_role[((i*2+1)*B + b)*NS + (d-133)];  tab = 1;     code = 5; }
        pk[s] = idx | (tab << 20) | (code << 22);
    }
    const int pkv0 = pk[0], pkv1 = pk[1], pkv2 = pk[2];

    // ---- node embedding fragment: quarter-wave layout, 8 dims/lane ----
    const int l16     = lane & 15;
    const int quarter = lane >> 4;
    const int nrow    = nodes_idx[i*B + b];
    const float4* nep = (const float4*)(node_tables + ((size_t)i*V + (size_t)nrow)*D) + l16*2;
    const float4 ne0 = nep[0];
    const float4 ne1 = nep[1];

    float acc = 0.0f;

    // entry for pipeline stage tt (tt in [0,42); tt>=36 hits zero-weight pads)
    auto gete = [&](int tt) -> int {
        int pks = (tt < 16) ? pkv0 : (tt < 32) ? pkv1 : pkv2;
        return __shfl(pks, (4*tt + quarter) & 63, 64);
    };
    auto loadrow = [&](int e, float4& r0, float4& r1) {
        int idx = e & 0xFFFFF;
        int tab = (e >> 20) & 3;
        const float* base = (tab & 2) ? neigh_tables : node_tables;
        const float4* row = (const float4*)(base + ((size_t)(tab & 1)*V + (size_t)idx)*D) + l16*2;
        r0 = row[0];
        r1 = row[1];
    };
    // compute entry in (r0,r1,e), then refill the stage with entry tt+3
    auto stepf = [&](int tt, float4& r0, float4& r1, int& e) {
        float pp = dot8(ne0, ne1, r0, r1);
        pp += __shfl_xor(pp, 1, 64);
        pp += __shfl_xor(pp, 2, 64);
        pp += __shfl_xor(pp, 4, 64);
        pp += __shfl_xor(pp, 8, 64);
        acc += wlogsig(pp, (e >> 22) & 7);
        e = gete(tt + 3);
        loadrow(e, r0, r1);
    };

    // depth-3 register pipeline: 39 uniform steps, entries 36..41 are zero-weight pads
    int e0 = gete(0), e1 = gete(1), e2 = gete(2);
    float4 a0, a1, b0, b1, c0, c1;
    loadrow(e0, a0, a1);
    loadrow(e1, b0, b1);
    loadrow(e2, c0, c1);

    #pragma unroll
    for (int t = 0; t < 39; t += 3) {
        stepf(t,     a0, a1, e0);
        stepf(t + 1, b0, b1, e1);
        stepf(t + 2, c0, c1, e2);
    }

    // acc replicated within each quarter; xor16+xor32 adds one rep per quarter
    acc += __shfl_xor(acc, 16, 64);
    acc += __shfl_xor(acc, 32, 64);

    __shared__ float wsum[4];
    if (lane == 0) wsum[wave] = acc;
    __syncthreads();
    if (tid == 0) {
        float s = wsum[0] + wsum[1] + wsum[2] + wsum[3];
        atomicAdd(out, s * (-1.0f / 10.0f));
    }
}

extern "C" void kernel_launch(void* const* d_in, const int* in_sizes, int n_in,
                              void* d_out, int out_size, void* d_ws, size_t ws_size,
                              hipStream_t stream) {
    const float* node_tables  = (const float*)d_in[0];
    const float* neigh_tables = (const float*)d_in[1];
    const int*   nodes_idx    = (const int*)d_in[2];
    const int*   neigh_idx    = (const int*)d_in[3];
    const int*   role_idx     = (const int*)d_in[4];
    const int*   neg_main     = (const int*)d_in[5];
    const int*   neg_node     = (const int*)d_in[6];
    const int*   neg_cross    = (const int*)d_in[7];
    const int*   neg_role     = (const int*)d_in[8];
    float* out = (float*)d_out;

    hipMemsetAsync(out, 0, sizeof(float), stream);
    rmne_main<<<2048, 256, 0, stream>>>(node_tables, neigh_tables, nodes_idx, neigh_idx,
                                        role_idx, neg_main, neg_node, neg_cross, neg_role, out);
}